// Round 1
// baseline (465.903 us; speedup 1.0000x reference)
//
#include <hip/hip_runtime.h>

// Timeseries AR(1) recurrence with per-step K-gather.
// T=1000 sequential steps; rows b independent. One wave (64 lanes) per row,
// 2 elements per lane (k=2l, 2l+1). Gather via in-wave __shfl (ds_bpermute),
// no LDS/barriers. Depth-8 explicit prefetch of eps/perm (static reg indices).

#define TT 1000
#define BB 512
#define KK 128
#define PD 8   // prefetch depth (TT % PD == 0)

__global__ __launch_bounds__(64) void ts_kernel(
    const float* __restrict__ init_state,
    const float* __restrict__ eps,
    const float* __restrict__ mult,
    const float* __restrict__ scale,
    const int*   __restrict__ perm,
    float*       __restrict__ out)
{
    const int b = blockIdx.x;    // 512 blocks, one row each
    const int l = threadIdx.x;   // 64 lanes
    const float m = mult[0];
    const float s = scale[0];

    // state: k = 2l (st.x), 2l+1 (st.y)
    float2 st = *reinterpret_cast<const float2*>(init_state + (size_t)b * KK + 2 * l);

    const float2* __restrict__ epsv  = reinterpret_cast<const float2*>(eps);
    const int2*   __restrict__ permv = reinterpret_cast<const int2*>(perm);
    float2*       __restrict__ outv  = reinterpret_cast<float2*>(out);

    const int KH = KK / 2; // 64 float2 per row

    float2 ebuf[PD];
    int2   pbuf[PD];
#pragma unroll
    for (int j = 0; j < PD; ++j) {
        ebuf[j] = epsv[((size_t)j * BB + b) * KH + l];
        pbuf[j] = permv[(size_t)j * KH + l];
    }

    for (int t0 = 0; t0 < TT; t0 += PD) {
#pragma unroll
        for (int j = 0; j < PD; ++j) {
            const int t = t0 + j;
            const float2 e = ebuf[j];
            const int2   p = pbuf[j];

            float2 samp;
            samp.x = fmaf(m, st.x, s * e.x);
            samp.y = fmaf(m, st.y, s * e.y);

            outv[((size_t)t * BB + b) * KH + l] = samp;

            // prefetch step t+PD into slot j (clamped; tail reloads are harmless)
            int tn = t + PD;
            if (tn > TT - 1) tn = TT - 1;
            ebuf[j] = epsv[((size_t)tn * BB + b) * KH + l];
            pbuf[j] = permv[(size_t)tn * KH + l];

            // gather: new_state[k] = samp[perm[t][k]]
            // value k' lives at lane k'>>1, slot k'&1
            const int l0 = p.x >> 1, l1 = p.y >> 1;
            float a0 = __shfl(samp.x, l0);
            float b0 = __shfl(samp.y, l0);
            float a1 = __shfl(samp.x, l1);
            float b1 = __shfl(samp.y, l1);
            st.x = (p.x & 1) ? b0 : a0;
            st.y = (p.y & 1) ? b1 : a1;
        }
    }
}

extern "C" void kernel_launch(void* const* d_in, const int* in_sizes, int n_in,
                              void* d_out, int out_size, void* d_ws, size_t ws_size,
                              hipStream_t stream) {
    const float* init_state = (const float*)d_in[0];
    const float* eps        = (const float*)d_in[1];
    const float* mult       = (const float*)d_in[2];
    const float* scale      = (const float*)d_in[3];
    const int*   perm       = (const int*)d_in[4];
    float*       out        = (float*)d_out;

    ts_kernel<<<dim3(BB), dim3(64), 0, stream>>>(init_state, eps, mult, scale, perm, out);
}